// Round 1
// 1782.563 us; speedup vs baseline: 1.0665x; 1.0665x over previous
//
#include <hip/hip_runtime.h>
#include <hip/hip_bf16.h>

// Problem constants
#define TT 2048
#define KK 6
#define EE 32
#define DD 2048
#define FF 1408
#define SS 2
#define CC 384   // TT*KK/EE

typedef __bf16 bf16_t;
typedef __attribute__((ext_vector_type(8))) __bf16 bf16x8;
typedef __attribute__((ext_vector_type(4))) float f32x4;
typedef unsigned int u32;

#define AS1 __attribute__((address_space(1)))
#define AS3 __attribute__((address_space(3)))

__device__ __forceinline__ u32 f2bf(float f) {
    u32 u = __builtin_bit_cast(u32, f);
    return (u + 0x7fffu + ((u >> 16) & 1u)) >> 16;   // RNE, no NaN in data
}
__device__ __forceinline__ u32 pack2(float a, float b) {
    return f2bf(a) | (f2bf(b) << 16);
}

// ---------------- dispatch: pair -> slot (balanced: exactly CC per expert) ----
__global__ void k_dispatch(const int* __restrict__ idx, int* __restrict__ counts,
                           int* __restrict__ tok, int* __restrict__ sop) {
    int p = blockIdx.x * 256 + threadIdx.x;
    if (p >= TT * KK) return;
    int e = idx[p];
    int pos = atomicAdd(&counts[e], 1);
    int slot = e * CC + pos;
    tok[slot] = p / KK;
    sop[p] = slot;
}

// ---------------- gather + fp32->bf16 convert --------------------------------
// rows [0, EE*CC): gathered routed inputs; rows [EE*CC, EE*CC+TT): x copy (shared)
__global__ void k_gather(const float* __restrict__ x, const int* __restrict__ tok,
                         bf16_t* __restrict__ xall) {
    int row = blockIdx.x;
    int srow = (row < EE * CC) ? tok[row] : (row - EE * CC);
    const float* src = x + (size_t)srow * DD;
    bf16_t* dst = xall + (size_t)row * DD;
    int c0 = threadIdx.x * 8;
    float4 a = *(const float4*)(src + c0);
    float4 b = *(const float4*)(src + c0 + 4);
    uint4 o;
    o.x = pack2(a.x, a.y); o.y = pack2(a.z, a.w);
    o.z = pack2(b.x, b.y); o.w = pack2(b.z, b.w);
    *(uint4*)(dst + c0) = o;
}

#define BSTR 40

// ---------------- routed grouped GEMM: whole expert M=384 per block ----------
// tile: M=384 (all of C) x N=64, BK=32. 4 waves, each wave 96 rows (6x4 frags).
// B (fp32 weights) is read EXACTLY ONCE per (n-tile, expert).
// A staged via global_load_lds with pre-swizzled source (slot ^= row&3) so the
// ds_read_b128 fragment reads drop from 8-way to 4-way bank conflict.
__global__ __launch_bounds__(256) void k_gemm_r(
    const bf16_t* __restrict__ Aall, const float* __restrict__ Br,
    bf16_t* __restrict__ Out, int Kdim, int N)
{
    const int e = blockIdx.y;
    const int n0 = blockIdx.x * 64;
    const bf16_t* A = Aall + (size_t)e * CC * Kdim;
    const float* Bp = Br + (size_t)e * Kdim * N + n0;
    bf16_t* Cout = Out + (size_t)e * CC * N + n0;

    __shared__ __align__(16) bf16_t As[CC * 32];     // 384x32 bf16 = 24 KB
    __shared__ __align__(16) bf16_t Bs[64 * BSTR];   // [n][k] transposed, 5 KB

    const int tid = threadIdx.x;
    const int lane = tid & 63, wid = tid >> 6;
    const int m_base = wid * 96;
    const int l15 = lane & 15, lq = lane >> 4;

    f32x4 acc[6][4] = {};

    const int arow = tid >> 2;        // row within 64-row stripe
    const int ac   = tid & 3;         // 16B slot within 64B row
    const int bn = tid & 63, kb = (tid >> 6) * 8;

    const int ksteps = Kdim >> 5;
    for (int kt = 0; kt < ksteps; ++kt) {
        const int k0 = kt << 5;
        // --- A: 384x32 via async global->LDS (linear dest, swizzled source) ---
        #pragma unroll
        for (int i = 0; i < 6; ++i) {
            const int row = i * 64 + arow;
            const int cs = ac ^ (row & 3);
            const bf16_t* g = A + (size_t)row * Kdim + (k0 + cs * 8);
            AS3 u32* l = (AS3 u32*)(void*)(As + (size_t)(i * 64 + wid * 16) * 32);
            __builtin_amdgcn_global_load_lds((const AS1 u32*)(const void*)g, l, 16, 0, 0);
        }
        // --- B: 32x64 fp32 coalesced load, cvt->bf16, transposed LDS write ---
        {
            const float* bg = Bp + (size_t)(k0 + kb) * N + bn;
            float v[8];
            #pragma unroll
            for (int j = 0; j < 8; ++j) v[j] = bg[(size_t)j * N];
            uint4 w;
            w.x = pack2(v[0], v[1]); w.y = pack2(v[2], v[3]);
            w.z = pack2(v[4], v[5]); w.w = pack2(v[6], v[7]);
            *(uint4*)(Bs + (size_t)bn * BSTR + kb) = w;
        }
        __syncthreads();
        bf16x8 bfr[4];
        #pragma unroll
        for (int j = 0; j < 4; ++j)
            bfr[j] = *(const bf16x8*)(Bs + (size_t)(j * 16 + l15) * BSTR + lq * 8);
        #pragma unroll
        for (int m = 0; m < 6; ++m) {
            const int row = m_base + m * 16 + l15;
            bf16x8 af = *(const bf16x8*)(As + (size_t)row * 32 + (size_t)((lq ^ (row & 3)) * 8));
            #pragma unroll
            for (int j = 0; j < 4; ++j)
                acc[m][j] = __builtin_amdgcn_mfma_f32_16x16x32_bf16(af, bfr[j], acc[m][j], 0, 0, 0);
        }
        __syncthreads();
    }

    // epilogue: C/D layout col=lane&15, row=quad*4+reg
    #pragma unroll
    for (int m = 0; m < 6; ++m) {
        #pragma unroll
        for (int j = 0; j < 4; ++j) {
            const int n = j * 16 + l15;
            #pragma unroll
            for (int r = 0; r < 4; ++r) {
                const int mm = m_base + m * 16 + lq * 4 + r;
                Cout[(size_t)mm * N + n] = (bf16_t)acc[m][j][r];
            }
        }
    }
}

// ---------------- shared-expert GEMM: 128x128 tile (weights are L3-resident) --
__global__ __launch_bounds__(256) void k_gemm_s(
    const bf16_t* __restrict__ Ash, const float* __restrict__ Bsh,
    bf16_t* __restrict__ Out, int Kdim, int N, int ash_stride)
{
    const int s = blockIdx.z;
    const bf16_t* A = Ash + ((size_t)s * ash_stride + (size_t)blockIdx.y * 128) * Kdim;
    bf16_t* Cout = Out + ((size_t)s * TT + (size_t)blockIdx.y * 128) * N + (size_t)blockIdx.x * 128;
    const float* Bp = Bsh + (size_t)s * Kdim * N + (size_t)blockIdx.x * 128;

    __shared__ __align__(16) bf16_t As[128 * 32];
    __shared__ __align__(16) bf16_t Bs[128 * BSTR];

    const int tid = threadIdx.x;
    const int lane = tid & 63, wid = tid >> 6;
    const int m_off = (wid >> 1) * 64, n_off = (wid & 1) * 64;
    const int l15 = lane & 15, lq = lane >> 4;

    f32x4 acc[4][4] = {};

    const int arow = tid >> 2;
    const int ac   = tid & 3;
    const int bn = tid & 127, kb = (tid >> 7) * 16;

    const int ksteps = Kdim >> 5;
    for (int kt = 0; kt < ksteps; ++kt) {
        const int k0 = kt << 5;
        {
            const int cs = ac ^ (arow & 3);   // (arow+64)&3 == arow&3
            const bf16_t* g0 = A + (size_t)arow * Kdim + (k0 + cs * 8);
            const bf16_t* g1 = A + (size_t)(arow + 64) * Kdim + (k0 + cs * 8);
            AS3 u32* l0 = (AS3 u32*)(void*)(As + (size_t)(wid * 16) * 32);
            AS3 u32* l1 = (AS3 u32*)(void*)(As + (size_t)(64 + wid * 16) * 32);
            __builtin_amdgcn_global_load_lds((const AS1 u32*)(const void*)g0, l0, 16, 0, 0);
            __builtin_amdgcn_global_load_lds((const AS1 u32*)(const void*)g1, l1, 16, 0, 0);
        }
        {
            const float* bg = Bp + (size_t)(k0 + kb) * N + bn;
            float v[16];
            #pragma unroll
            for (int j = 0; j < 16; ++j) v[j] = bg[(size_t)j * N];
            u32 p[8];
            #pragma unroll
            for (int j = 0; j < 8; ++j) p[j] = pack2(v[2 * j], v[2 * j + 1]);
            uint4 w0, w1;
            w0.x = p[0]; w0.y = p[1]; w0.z = p[2]; w0.w = p[3];
            w1.x = p[4]; w1.y = p[5]; w1.z = p[6]; w1.w = p[7];
            *(uint4*)(Bs + (size_t)bn * BSTR + kb) = w0;
            *(uint4*)(Bs + (size_t)bn * BSTR + kb + 8) = w1;
        }
        __syncthreads();
        bf16x8 af[4], bfr[4];
        #pragma unroll
        for (int i = 0; i < 4; ++i) {
            const int row = m_off + i * 16 + l15;
            af[i] = *(const bf16x8*)(As + (size_t)row * 32 + (size_t)((lq ^ (row & 3)) * 8));
        }
        #pragma unroll
        for (int j = 0; j < 4; ++j)
            bfr[j] = *(const bf16x8*)(Bs + (size_t)(n_off + j * 16 + l15) * BSTR + lq * 8);
        #pragma unroll
        for (int i = 0; i < 4; ++i)
            #pragma unroll
            for (int j = 0; j < 4; ++j)
                acc[i][j] = __builtin_amdgcn_mfma_f32_16x16x32_bf16(af[i], bfr[j], acc[i][j], 0, 0, 0);
        __syncthreads();
    }

    #pragma unroll
    for (int i = 0; i < 4; ++i) {
        #pragma unroll
        for (int j = 0; j < 4; ++j) {
            int n = n_off + j * 16 + l15;
            #pragma unroll
            for (int r = 0; r < 4; ++r) {
                int m = m_off + i * 16 + lq * 4 + r;
                Cout[(size_t)m * N + n] = (bf16_t)acc[i][j][r];
            }
        }
    }
}

// ---------------- silu(gate) * up ------------------------------------------
__global__ void k_silu(const bf16_t* __restrict__ gu, bf16_t* __restrict__ act) {
    u32 f = ((u32)blockIdx.x * 256 + threadIdx.x) * 8;
    u32 row = f / FF;
    u32 col = f % FF;
    const bf16_t* base = gu + (size_t)row * (2 * FF) + col;
    bf16x8 g = *(const bf16x8*)(base);
    bf16x8 u = *(const bf16x8*)(base + FF);
    bf16x8 ov;
    #pragma unroll
    for (int j = 0; j < 8; ++j) {
        float gf = (float)g[j], uf = (float)u[j];
        float s = gf / (1.0f + __expf(-gf));
        ov[j] = (bf16_t)(s * uf);
    }
    *(bf16x8*)(act + (size_t)row * FF + col) = ov;
}

// ---------------- combine: weighted scatter of routed + shared add ----------
__global__ void k_combine(const bf16_t* __restrict__ down, const int* __restrict__ sop,
                          const float* __restrict__ wts, float* __restrict__ y) {
    int t = blockIdx.x;
    int d0 = threadIdx.x * 8;
    float a[8] = {0, 0, 0, 0, 0, 0, 0, 0};
    #pragma unroll
    for (int k = 0; k < KK; ++k) {
        int slot = sop[t * KK + k];
        float w = wts[t * KK + k];
        bf16x8 v = *(const bf16x8*)(down + (size_t)slot * DD + d0);
        #pragma unroll
        for (int j = 0; j < 8; ++j) a[j] += w * (float)v[j];
    }
    #pragma unroll
    for (int s = 0; s < SS; ++s) {
        bf16x8 v = *(const bf16x8*)(down + ((size_t)EE * CC + (size_t)s * TT + t) * DD + d0);
        #pragma unroll
        for (int j = 0; j < 8; ++j) a[j] += (float)v[j];
    }
    float4 o0, o1;
    o0.x = a[0]; o0.y = a[1]; o0.z = a[2]; o0.w = a[3];
    o1.x = a[4]; o1.y = a[5]; o1.z = a[6]; o1.w = a[7];
    *(float4*)(y + (size_t)t * DD + d0) = o0;
    *(float4*)(y + (size_t)t * DD + d0 + 4) = o1;
}

extern "C" void kernel_launch(void* const* d_in, const int* in_sizes, int n_in,
                              void* d_out, int out_size, void* d_ws, size_t ws_size,
                              hipStream_t stream) {
    (void)in_sizes; (void)n_in; (void)out_size; (void)ws_size;
    const float* x      = (const float*)d_in[0];
    const float* wts    = (const float*)d_in[1];
    const float* w_gu   = (const float*)d_in[2];
    const float* w_dn   = (const float*)d_in[3];
    const float* w_gu_s = (const float*)d_in[4];
    const float* w_dn_s = (const float*)d_in[5];
    const int*   indices= (const int*)d_in[6];
    float* y = (float*)d_out;

    char* ws = (char*)d_ws;
    size_t off = 0;
    auto alloc = [&](size_t bytes) {
        void* p = ws + off;
        off = (off + bytes + 255) & ~(size_t)255;
        return p;
    };
    int*    counts = (int*)alloc((size_t)EE * 4);
    int*    tok    = (int*)alloc((size_t)EE * CC * 4);
    int*    sop    = (int*)alloc((size_t)TT * KK * 4);
    bf16_t* xall   = (bf16_t*)alloc((size_t)(EE * CC + TT) * DD * 2);
    bf16_t* gu     = (bf16_t*)alloc((size_t)(EE * CC + SS * TT) * 2 * FF * 2);
    bf16_t* actb   = (bf16_t*)alloc((size_t)(EE * CC + SS * TT) * FF * 2);
    bf16_t* dnout  = (bf16_t*)alloc((size_t)(EE * CC + SS * TT) * DD * 2);

    hipMemsetAsync(counts, 0, EE * 4, stream);
    k_dispatch<<<(TT * KK + 255) / 256, 256, 0, stream>>>(indices, counts, tok, sop);
    k_gather<<<EE * CC + TT, 256, 0, stream>>>(x, tok, xall);

    // ---- gate_up: K=DD, N=2*FF ----
    // routed: whole-expert M-tile, weights read once
    k_gemm_r<<<dim3(2 * FF / 64, EE), 256, 0, stream>>>(xall, w_gu, gu, DD, 2 * FF);
    // shared: both s groups read the same x-copy rows (ash_stride=0)
    k_gemm_s<<<dim3(2 * FF / 128, TT / 128, SS), 256, 0, stream>>>(
        xall + (size_t)EE * CC * DD, w_gu_s, gu + (size_t)EE * CC * 2 * FF, DD, 2 * FF, 0);

    k_silu<<<(EE * CC + SS * TT) * FF / 8 / 256, 256, 0, stream>>>(gu, actb);

    // ---- down: K=FF, N=DD ----
    k_gemm_r<<<dim3(DD / 64, EE), 256, 0, stream>>>(actb, w_dn, dnout, FF, DD);
    k_gemm_s<<<dim3(DD / 128, TT / 128, SS), 256, 0, stream>>>(
        actb + (size_t)EE * CC * FF, w_dn_s, dnout + (size_t)EE * CC * DD, FF, DD, TT);

    k_combine<<<TT, 256, 0, stream>>>(dnout, sop, wts, y);
}

// Round 2
// 1614.465 us; speedup vs baseline: 1.1776x; 1.1041x over previous
//
#include <hip/hip_runtime.h>
#include <hip/hip_bf16.h>

// Problem constants
#define TT 2048
#define KK 6
#define EE 32
#define DD 2048
#define FF 1408
#define SS 2
#define CC 384   // TT*KK/EE

typedef __bf16 bf16_t;
typedef __attribute__((ext_vector_type(8))) __bf16 bf16x8;
typedef __attribute__((ext_vector_type(4))) float f32x4;
typedef unsigned int u32;

#define AS1 __attribute__((address_space(1)))
#define AS3 __attribute__((address_space(3)))

__device__ __forceinline__ u32 f2bf(float f) {
    u32 u = __builtin_bit_cast(u32, f);
    return (u + 0x7fffu + ((u >> 16) & 1u)) >> 16;   // RNE, no NaN in data
}
__device__ __forceinline__ u32 pack2(float a, float b) {
    return f2bf(a) | (f2bf(b) << 16);
}

// ---------------- dispatch: pair -> slot (balanced: exactly CC per expert) ----
__global__ void k_dispatch(const int* __restrict__ idx, int* __restrict__ counts,
                           int* __restrict__ tok, int* __restrict__ sop) {
    int p = blockIdx.x * 256 + threadIdx.x;
    if (p >= TT * KK) return;
    int e = idx[p];
    int pos = atomicAdd(&counts[e], 1);
    int slot = e * CC + pos;
    tok[slot] = p / KK;
    sop[p] = slot;
}

// ---------------- gather + fp32->bf16 convert --------------------------------
__global__ void k_gather(const float* __restrict__ x, const int* __restrict__ tok,
                         bf16_t* __restrict__ xall) {
    int row = blockIdx.x;
    int srow = (row < EE * CC) ? tok[row] : (row - EE * CC);
    const float* src = x + (size_t)srow * DD;
    bf16_t* dst = xall + (size_t)row * DD;
    int c0 = threadIdx.x * 8;
    float4 a = *(const float4*)(src + c0);
    float4 b = *(const float4*)(src + c0 + 4);
    uint4 o;
    o.x = pack2(a.x, a.y); o.y = pack2(a.z, a.w);
    o.z = pack2(b.x, b.y); o.w = pack2(b.z, b.w);
    *(uint4*)(dst + c0) = o;
}

#define BSTR 40

// A stage: 384 rows x 32 cols bf16 via global_load_lds, linear LDS dest,
// source pre-swizzled (slot ^= row&3) so fragment ds_read_b128 is 4-way not 8-way.
__device__ __forceinline__ void stage_a6(const bf16_t* __restrict__ A, int Kdim, int k0,
                                         bf16_t* dst, int arow, int ac, int wid) {
    #pragma unroll
    for (int i = 0; i < 6; ++i) {
        const int row = i * 64 + arow;
        const int cs = ac ^ (row & 3);
        const bf16_t* g = A + (size_t)row * Kdim + (k0 + cs * 8);
        AS3 u32* l = (AS3 u32*)(void*)(dst + (size_t)(i * 64 + wid * 16) * 32);
        __builtin_amdgcn_global_load_lds((const AS1 u32*)(const void*)g, l, 16, 0, 0);
    }
}

// ---------------- routed grouped GEMM: whole expert M=384 per block ----------
// tile M=384 x N=64, BK=32, 4 waves (wave tile 96x64, 6x4 frags).
// Double-buffered 2-phase pipeline: STAGE(next) issued before compute(cur),
// B staged global->reg (early) -> pack+ds_write (late), one barrier per K-step.
__global__ __launch_bounds__(256) void k_gemm_r(
    const bf16_t* __restrict__ Aall, const float* __restrict__ Br,
    bf16_t* __restrict__ Out, int Kdim, int N)
{
    const int e = blockIdx.y;
    const int n0 = blockIdx.x * 64;
    const bf16_t* A = Aall + (size_t)e * CC * Kdim;
    const float* Bp = Br + (size_t)e * Kdim * N + n0;
    bf16_t* Cout = Out + (size_t)e * CC * N + n0;

    __shared__ __align__(16) bf16_t As[2][CC * 32];     // 2 x 24 KB
    __shared__ __align__(16) bf16_t Bs[2][64 * BSTR];   // 2 x 5 KB

    const int tid = threadIdx.x;
    const int lane = tid & 63, wid = tid >> 6;
    const int m_base = wid * 96;
    const int l15 = lane & 15, lq = lane >> 4;

    f32x4 acc[6][4] = {};

    const int arow = tid >> 2;        // 0..63 within each 64-row stripe
    const int ac   = tid & 3;
    const int bn = tid & 63, kb = (tid >> 6) * 8;

    const int ksteps = Kdim >> 5;

    // ---- prologue: fully stage tile 0 into buffer 0 ----
    {
        stage_a6(A, Kdim, 0, &As[0][0], arow, ac, wid);
        const float* bg = Bp + (size_t)kb * N + bn;
        float v[8];
        #pragma unroll
        for (int j = 0; j < 8; ++j) v[j] = bg[(size_t)j * N];
        uint4 w;
        w.x = pack2(v[0], v[1]); w.y = pack2(v[2], v[3]);
        w.z = pack2(v[4], v[5]); w.w = pack2(v[6], v[7]);
        *(uint4*)(&Bs[0][0] + (size_t)bn * BSTR + kb) = w;
    }
    __syncthreads();

    int cur = 0;
    for (int kt = 0; kt < ksteps; ++kt) {
        const bool pf = (kt + 1 < ksteps);
        float vn[8];
        if (pf) {
            const int k1 = (kt + 1) << 5;
            // issue next A tile (async -> LDS) and next B rows (-> regs) EARLY
            stage_a6(A, Kdim, k1, &As[cur ^ 1][0], arow, ac, wid);
            const float* bg = Bp + (size_t)(k1 + kb) * N + bn;
            #pragma unroll
            for (int j = 0; j < 8; ++j) vn[j] = bg[(size_t)j * N];
        }
        // ---- compute on cur ----
        bf16x8 bfr[4];
        #pragma unroll
        for (int j = 0; j < 4; ++j)
            bfr[j] = *(const bf16x8*)(&Bs[cur][0] + (size_t)(j * 16 + l15) * BSTR + lq * 8);
        #pragma unroll
        for (int m = 0; m < 6; ++m) {
            const int row = m_base + m * 16 + l15;
            bf16x8 af = *(const bf16x8*)(&As[cur][0] + (size_t)row * 32 + (size_t)((lq ^ (row & 3)) * 8));
            #pragma unroll
            for (int j = 0; j < 4; ++j)
                acc[m][j] = __builtin_amdgcn_mfma_f32_16x16x32_bf16(af, bfr[j], acc[m][j], 0, 0, 0);
        }
        // ---- late half of B stage: pack + LDS write into next buffer ----
        if (pf) {
            uint4 w;
            w.x = pack2(vn[0], vn[1]); w.y = pack2(vn[2], vn[3]);
            w.z = pack2(vn[4], vn[5]); w.w = pack2(vn[6], vn[7]);
            *(uint4*)(&Bs[cur ^ 1][0] + (size_t)bn * BSTR + kb) = w;
        }
        __syncthreads();
        cur ^= 1;
    }

    // epilogue: C/D layout col=lane&15, row=quad*4+reg
    #pragma unroll
    for (int m = 0; m < 6; ++m) {
        #pragma unroll
        for (int j = 0; j < 4; ++j) {
            const int n = j * 16 + l15;
            #pragma unroll
            for (int r = 0; r < 4; ++r) {
                const int mm = m_base + m * 16 + lq * 4 + r;
                Cout[(size_t)mm * N + n] = (bf16_t)acc[m][j][r];
            }
        }
    }
}

// ---------------- shared-expert GEMM: 128x128 tile, same 2-phase pipeline ----
__global__ __launch_bounds__(256) void k_gemm_s(
    const bf16_t* __restrict__ Ash, const float* __restrict__ Bsh,
    bf16_t* __restrict__ Out, int Kdim, int N, int ash_stride)
{
    const int s = blockIdx.z;
    const bf16_t* A = Ash + ((size_t)s * ash_stride + (size_t)blockIdx.y * 128) * Kdim;
    bf16_t* Cout = Out + ((size_t)s * TT + (size_t)blockIdx.y * 128) * N + (size_t)blockIdx.x * 128;
    const float* Bp = Bsh + (size_t)s * Kdim * N + (size_t)blockIdx.x * 128;

    __shared__ __align__(16) bf16_t As[2][128 * 32];    // 2 x 8 KB
    __shared__ __align__(16) bf16_t Bs[2][128 * BSTR];  // 2 x 10 KB

    const int tid = threadIdx.x;
    const int lane = tid & 63, wid = tid >> 6;
    const int m_off = (wid >> 1) * 64, n_off = (wid & 1) * 64;
    const int l15 = lane & 15, lq = lane >> 4;

    f32x4 acc[4][4] = {};

    const int arow = tid >> 2;
    const int ac   = tid & 3;
    const int bn = tid & 127, kb = (tid >> 7) * 16;

    const int ksteps = Kdim >> 5;

    auto stageA = [&](int b, int k0) {
        const int cs = ac ^ (arow & 3);   // (arow+64)&3 == arow&3
        const bf16_t* g0 = A + (size_t)arow * Kdim + (k0 + cs * 8);
        const bf16_t* g1 = A + (size_t)(arow + 64) * Kdim + (k0 + cs * 8);
        AS3 u32* l0 = (AS3 u32*)(void*)(&As[b][0] + (size_t)(wid * 16) * 32);
        AS3 u32* l1 = (AS3 u32*)(void*)(&As[b][0] + (size_t)(64 + wid * 16) * 32);
        __builtin_amdgcn_global_load_lds((const AS1 u32*)(const void*)g0, l0, 16, 0, 0);
        __builtin_amdgcn_global_load_lds((const AS1 u32*)(const void*)g1, l1, 16, 0, 0);
    };

    // ---- prologue ----
    {
        stageA(0, 0);
        const float* bg = Bp + (size_t)kb * N + bn;
        float v[16];
        #pragma unroll
        for (int j = 0; j < 16; ++j) v[j] = bg[(size_t)j * N];
        u32 p[8];
        #pragma unroll
        for (int j = 0; j < 8; ++j) p[j] = pack2(v[2 * j], v[2 * j + 1]);
        uint4 w0, w1;
        w0.x = p[0]; w0.y = p[1]; w0.z = p[2]; w0.w = p[3];
        w1.x = p[4]; w1.y = p[5]; w1.z = p[6]; w1.w = p[7];
        *(uint4*)(&Bs[0][0] + (size_t)bn * BSTR + kb) = w0;
        *(uint4*)(&Bs[0][0] + (size_t)bn * BSTR + kb + 8) = w1;
    }
    __syncthreads();

    int cur = 0;
    for (int kt = 0; kt < ksteps; ++kt) {
        const bool pf = (kt + 1 < ksteps);
        float vn[16];
        if (pf) {
            const int k1 = (kt + 1) << 5;
            stageA(cur ^ 1, k1);
            const float* bg = Bp + (size_t)(k1 + kb) * N + bn;
            #pragma unroll
            for (int j = 0; j < 16; ++j) vn[j] = bg[(size_t)j * N];
        }
        // ---- compute on cur ----
        bf16x8 af[4], bfr[4];
        #pragma unroll
        for (int i = 0; i < 4; ++i) {
            const int row = m_off + i * 16 + l15;
            af[i] = *(const bf16x8*)(&As[cur][0] + (size_t)row * 32 + (size_t)((lq ^ (row & 3)) * 8));
        }
        #pragma unroll
        for (int j = 0; j < 4; ++j)
            bfr[j] = *(const bf16x8*)(&Bs[cur][0] + (size_t)(n_off + j * 16 + l15) * BSTR + lq * 8);
        #pragma unroll
        for (int i = 0; i < 4; ++i)
            #pragma unroll
            for (int j = 0; j < 4; ++j)
                acc[i][j] = __builtin_amdgcn_mfma_f32_16x16x32_bf16(af[i], bfr[j], acc[i][j], 0, 0, 0);
        // ---- late half of B stage ----
        if (pf) {
            u32 p[8];
            #pragma unroll
            for (int j = 0; j < 8; ++j) p[j] = pack2(vn[2 * j], vn[2 * j + 1]);
            uint4 w0, w1;
            w0.x = p[0]; w0.y = p[1]; w0.z = p[2]; w0.w = p[3];
            w1.x = p[4]; w1.y = p[5]; w1.z = p[6]; w1.w = p[7];
            *(uint4*)(&Bs[cur ^ 1][0] + (size_t)bn * BSTR + kb) = w0;
            *(uint4*)(&Bs[cur ^ 1][0] + (size_t)bn * BSTR + kb + 8) = w1;
        }
        __syncthreads();
        cur ^= 1;
    }

    #pragma unroll
    for (int i = 0; i < 4; ++i) {
        #pragma unroll
        for (int j = 0; j < 4; ++j) {
            int n = n_off + j * 16 + l15;
            #pragma unroll
            for (int r = 0; r < 4; ++r) {
                int m = m_off + i * 16 + lq * 4 + r;
                Cout[(size_t)m * N + n] = (bf16_t)acc[i][j][r];
            }
        }
    }
}

// ---------------- silu(gate) * up ------------------------------------------
__global__ void k_silu(const bf16_t* __restrict__ gu, bf16_t* __restrict__ act) {
    u32 f = ((u32)blockIdx.x * 256 + threadIdx.x) * 8;
    u32 row = f / FF;
    u32 col = f % FF;
    const bf16_t* base = gu + (size_t)row * (2 * FF) + col;
    bf16x8 g = *(const bf16x8*)(base);
    bf16x8 u = *(const bf16x8*)(base + FF);
    bf16x8 ov;
    #pragma unroll
    for (int j = 0; j < 8; ++j) {
        float gf = (float)g[j], uf = (float)u[j];
        float s = gf / (1.0f + __expf(-gf));
        ov[j] = (bf16_t)(s * uf);
    }
    *(bf16x8*)(act + (size_t)row * FF + col) = ov;
}

// ---------------- combine: weighted scatter of routed + shared add ----------
__global__ void k_combine(const bf16_t* __restrict__ down, const int* __restrict__ sop,
                          const float* __restrict__ wts, float* __restrict__ y) {
    int t = blockIdx.x;
    int d0 = threadIdx.x * 8;
    float a[8] = {0, 0, 0, 0, 0, 0, 0, 0};
    #pragma unroll
    for (int k = 0; k < KK; ++k) {
        int slot = sop[t * KK + k];
        float w = wts[t * KK + k];
        bf16x8 v = *(const bf16x8*)(down + (size_t)slot * DD + d0);
        #pragma unroll
        for (int j = 0; j < 8; ++j) a[j] += w * (float)v[j];
    }
    #pragma unroll
    for (int s = 0; s < SS; ++s) {
        bf16x8 v = *(const bf16x8*)(down + ((size_t)EE * CC + (size_t)s * TT + t) * DD + d0);
        #pragma unroll
        for (int j = 0; j < 8; ++j) a[j] += (float)v[j];
    }
    float4 o0, o1;
    o0.x = a[0]; o0.y = a[1]; o0.z = a[2]; o0.w = a[3];
    o1.x = a[4]; o1.y = a[5]; o1.z = a[6]; o1.w = a[7];
    *(float4*)(y + (size_t)t * DD + d0) = o0;
    *(float4*)(y + (size_t)t * DD + d0 + 4) = o1;
}

extern "C" void kernel_launch(void* const* d_in, const int* in_sizes, int n_in,
                              void* d_out, int out_size, void* d_ws, size_t ws_size,
                              hipStream_t stream) {
    (void)in_sizes; (void)n_in; (void)out_size; (void)ws_size;
    const float* x      = (const float*)d_in[0];
    const float* wts    = (const float*)d_in[1];
    const float* w_gu   = (const float*)d_in[2];
    const float* w_dn   = (const float*)d_in[3];
    const float* w_gu_s = (const float*)d_in[4];
    const float* w_dn_s = (const float*)d_in[5];
    const int*   indices= (const int*)d_in[6];
    float* y = (float*)d_out;

    char* ws = (char*)d_ws;
    size_t off = 0;
    auto alloc = [&](size_t bytes) {
        void* p = ws + off;
        off = (off + bytes + 255) & ~(size_t)255;
        return p;
    };
    int*    counts = (int*)alloc((size_t)EE * 4);
    int*    tok    = (int*)alloc((size_t)EE * CC * 4);
    int*    sop    = (int*)alloc((size_t)TT * KK * 4);
    bf16_t* xall   = (bf16_t*)alloc((size_t)(EE * CC + TT) * DD * 2);
    bf16_t* gu     = (bf16_t*)alloc((size_t)(EE * CC + SS * TT) * 2 * FF * 2);
    bf16_t* actb   = (bf16_t*)alloc((size_t)(EE * CC + SS * TT) * FF * 2);
    bf16_t* dnout  = (bf16_t*)alloc((size_t)(EE * CC + SS * TT) * DD * 2);

    hipMemsetAsync(counts, 0, EE * 4, stream);
    k_dispatch<<<(TT * KK + 255) / 256, 256, 0, stream>>>(indices, counts, tok, sop);
    k_gather<<<EE * CC + TT, 256, 0, stream>>>(x, tok, xall);

    // ---- gate_up: K=DD, N=2*FF ----
    k_gemm_r<<<dim3(2 * FF / 64, EE), 256, 0, stream>>>(xall, w_gu, gu, DD, 2 * FF);
    k_gemm_s<<<dim3(2 * FF / 128, TT / 128, SS), 256, 0, stream>>>(
        xall + (size_t)EE * CC * DD, w_gu_s, gu + (size_t)EE * CC * 2 * FF, DD, 2 * FF, 0);

    k_silu<<<(EE * CC + SS * TT) * FF / 8 / 256, 256, 0, stream>>>(gu, actb);

    // ---- down: K=FF, N=DD ----
    k_gemm_r<<<dim3(DD / 64, EE), 256, 0, stream>>>(actb, w_dn, dnout, FF, DD);
    k_gemm_s<<<dim3(DD / 128, TT / 128, SS), 256, 0, stream>>>(
        actb + (size_t)EE * CC * FF, w_dn_s, dnout + (size_t)EE * CC * DD, FF, DD, TT);

    k_combine<<<TT, 256, 0, stream>>>(dnout, sop, wts, y);
}

// Round 3
// 1589.635 us; speedup vs baseline: 1.1960x; 1.0156x over previous
//
#include <hip/hip_runtime.h>
#include <hip/hip_bf16.h>

// Problem constants
#define TT 2048
#define KK 6
#define EE 32
#define DD 2048
#define FF 1408
#define SS 2
#define CC 384   // TT*KK/EE

typedef __bf16 bf16_t;
typedef __attribute__((ext_vector_type(8))) __bf16 bf16x8;
typedef __attribute__((ext_vector_type(4))) float f32x4;
typedef unsigned int u32;

#define AS1 __attribute__((address_space(1)))
#define AS3 __attribute__((address_space(3)))

__device__ __forceinline__ u32 f2bf(float f) {
    u32 u = __builtin_bit_cast(u32, f);
    return (u + 0x7fffu + ((u >> 16) & 1u)) >> 16;   // RNE, no NaN in data
}
__device__ __forceinline__ u32 pack2(float a, float b) {
    return f2bf(a) | (f2bf(b) << 16);
}
__device__ __forceinline__ float silu_mul(float g, float u) {
    return (g / (1.0f + __expf(-g))) * u;
}

// ---------------- dispatch: pair -> slot (balanced: exactly CC per expert) ----
__global__ void k_dispatch(const int* __restrict__ idx, int* __restrict__ counts,
                           int* __restrict__ tok, int* __restrict__ sop) {
    int p = blockIdx.x * 256 + threadIdx.x;
    if (p >= TT * KK) return;
    int e = idx[p];
    int pos = atomicAdd(&counts[e], 1);
    int slot = e * CC + pos;
    tok[slot] = p / KK;
    sop[p] = slot;
}

// ---------------- gather + fp32->bf16 convert --------------------------------
__global__ void k_gather(const float* __restrict__ x, const int* __restrict__ tok,
                         bf16_t* __restrict__ xall) {
    int row = blockIdx.x;
    int srow = (row < EE * CC) ? tok[row] : (row - EE * CC);
    const float* src = x + (size_t)srow * DD;
    bf16_t* dst = xall + (size_t)row * DD;
    int c0 = threadIdx.x * 8;
    float4 a = *(const float4*)(src + c0);
    float4 b = *(const float4*)(src + c0 + 4);
    uint4 o;
    o.x = pack2(a.x, a.y); o.y = pack2(a.z, a.w);
    o.z = pack2(b.x, b.y); o.w = pack2(b.z, b.w);
    *(uint4*)(dst + c0) = o;
}

#define BSTR 40

// A stage: 384x32 bf16 via global_load_lds, linear LDS dest, source pre-swizzled
// with slot ^= (row>>1)&3 -> fragment ds_read_b128 is 2-way (conflict-free).
__device__ __forceinline__ void stage_a6(const bf16_t* __restrict__ A, int Kdim, int k0,
                                         bf16_t* dst, int arow, int ac, int wid) {
    #pragma unroll
    for (int i = 0; i < 6; ++i) {
        const int row = i * 64 + arow;
        const int cs = ac ^ ((row >> 1) & 3);
        const bf16_t* g = A + (size_t)row * Kdim + (k0 + cs * 8);
        AS3 u32* l = (AS3 u32*)(void*)(dst + (size_t)(i * 64 + wid * 16) * 32);
        __builtin_amdgcn_global_load_lds((const AS1 u32*)(const void*)g, l, 16, 0, 0);
    }
}

// ---------------- routed grouped GEMM: whole expert M=384 per block ----------
// tile M=384 x N=64, BK=32, 4 waves (wave tile 96x64, 6x4 frags), 2-phase dbuf.
// XCD pinning: expert e's blocks all land on XCD e%8 so A re-reads hit that L2.
// FUSED: N = 32 gate cols + 32 up cols (same local col), silu*up in epilogue.
template<bool FUSED>
__global__ __launch_bounds__(256) void k_gemm_r(
    const bf16_t* __restrict__ Aall, const float* __restrict__ Br,
    bf16_t* __restrict__ Out, int Kdim, int Bstr, int Ostr, int NB)
{
    const int lin = blockIdx.x;
    const int xcd = lin & 7, jj = lin >> 3;
    const int e = xcd + 8 * (jj / NB);
    const int nblk = jj % NB;

    const bf16_t* A = Aall + (size_t)e * CC * Kdim;
    const float* Bbase = Br + (size_t)e * Kdim * Bstr;

    const int tid = threadIdx.x;
    const int lane = tid & 63, wid = tid >> 6;
    const int m_base = wid * 96;
    const int l15 = lane & 15, lq = lane >> 4;
    const int arow = tid >> 2, ac = tid & 3;
    const int kb = (tid >> 6) * 8;
    const int bn = tid & 63;

    const float* bsrc;
    bf16_t* Cout;
    if (FUSED) {
        const float* Bg = Bbase + nblk * 32;
        bsrc = (((tid >> 5) & 1) ? (Bg + FF) : Bg) + (tid & 31);
        Cout = Out + (size_t)e * CC * Ostr + nblk * 32;
    } else {
        bsrc = Bbase + nblk * 64 + bn;
        Cout = Out + (size_t)e * CC * Ostr + nblk * 64;
    }

    __shared__ __align__(16) bf16_t As[2][CC * 32];     // 2 x 24 KB
    __shared__ __align__(16) bf16_t Bs[2][64 * BSTR];   // 2 x 5 KB

    f32x4 acc[6][4] = {};
    const int ksteps = Kdim >> 5;

    auto loadB = [&](int k0, float* v) {
        const float* sp = bsrc + (size_t)(k0 + kb) * Bstr;
        #pragma unroll
        for (int t = 0; t < 8; ++t) v[t] = sp[(size_t)t * Bstr];
    };
    auto writeB = [&](int b, const float* v) {
        uint4 w;
        w.x = pack2(v[0], v[1]); w.y = pack2(v[2], v[3]);
        w.z = pack2(v[4], v[5]); w.w = pack2(v[6], v[7]);
        *(uint4*)(&Bs[b][0] + (size_t)bn * BSTR + kb) = w;
    };

    // ---- prologue: fully stage tile 0 ----
    {
        stage_a6(A, Kdim, 0, &As[0][0], arow, ac, wid);
        float v[8]; loadB(0, v); writeB(0, v);
    }
    __syncthreads();

    int cur = 0;
    for (int kt = 0; kt < ksteps; ++kt) {
        const bool pf = (kt + 1 < ksteps);
        float vn[8];
        if (pf) {
            const int k1 = (kt + 1) << 5;
            stage_a6(A, Kdim, k1, &As[cur ^ 1][0], arow, ac, wid);
            loadB(k1, vn);
        }
        bf16x8 bfr[4];
        #pragma unroll
        for (int j = 0; j < 4; ++j)
            bfr[j] = *(const bf16x8*)(&Bs[cur][0] + (size_t)(j * 16 + l15) * BSTR + lq * 8);
        #pragma unroll
        for (int m = 0; m < 6; ++m) {
            const int row = m_base + m * 16 + l15;
            bf16x8 af = *(const bf16x8*)(&As[cur][0] + (size_t)row * 32 + (size_t)((lq ^ ((row >> 1) & 3)) * 8));
            #pragma unroll
            for (int j = 0; j < 4; ++j)
                acc[m][j] = __builtin_amdgcn_mfma_f32_16x16x32_bf16(af, bfr[j], acc[m][j], 0, 0, 0);
        }
        if (pf) writeB(cur ^ 1, vn);
        __syncthreads();
        cur ^= 1;
    }

    // epilogue: C/D layout col=lane&15, row=quad*4+reg
    if (FUSED) {
        #pragma unroll
        for (int m = 0; m < 6; ++m)
            #pragma unroll
            for (int j = 0; j < 2; ++j) {
                const int n = j * 16 + l15;
                #pragma unroll
                for (int r = 0; r < 4; ++r) {
                    const int mm = m_base + m * 16 + lq * 4 + r;
                    Cout[(size_t)mm * Ostr + n] = (bf16_t)silu_mul(acc[m][j][r], acc[m][j + 2][r]);
                }
            }
    } else {
        #pragma unroll
        for (int m = 0; m < 6; ++m)
            #pragma unroll
            for (int j = 0; j < 4; ++j) {
                const int n = j * 16 + l15;
                #pragma unroll
                for (int r = 0; r < 4; ++r) {
                    const int mm = m_base + m * 16 + lq * 4 + r;
                    Cout[(size_t)mm * Ostr + n] = (bf16_t)acc[m][j][r];
                }
            }
    }
}

// ---------------- shared-expert GEMM: 128x128 tile, same 2-phase pipeline ----
// FUSED: block N = 64 gate + 64 up; wave wn owns gate [wn*32,+32) + matching up.
template<bool FUSED>
__global__ __launch_bounds__(256) void k_gemm_s(
    const bf16_t* __restrict__ Ash, const float* __restrict__ Bsh,
    bf16_t* __restrict__ Out, int Kdim, int Bstr, int Ostr, int ash_stride)
{
    const int s = blockIdx.z;
    const int n0 = blockIdx.x * (FUSED ? 64 : 128);
    const bf16_t* A = Ash + ((size_t)s * ash_stride + (size_t)blockIdx.y * 128) * Kdim;
    bf16_t* Cout = Out + ((size_t)s * TT + (size_t)blockIdx.y * 128) * Ostr + n0;
    const float* Bbase = Bsh + (size_t)s * Kdim * Bstr + n0;

    const int tid = threadIdx.x;
    const int lane = tid & 63, wid = tid >> 6;
    const int m_off = (wid >> 1) * 64, wn = wid & 1;
    const int l15 = lane & 15, lq = lane >> 4;
    const int arow = tid >> 2, ac = tid & 3;
    const int bn = tid & 127, kb = (tid >> 7) * 16;

    const float* bsrc;
    if (FUSED) bsrc = (((tid >> 6) & 1) ? (Bbase + FF) : Bbase) + (tid & 63);
    else       bsrc = Bbase + bn;

    __shared__ __align__(16) bf16_t As[2][128 * 32];    // 2 x 8 KB
    __shared__ __align__(16) bf16_t Bs[2][128 * BSTR];  // 2 x 10 KB

    f32x4 acc[4][4] = {};
    const int ksteps = Kdim >> 5;

    auto stageA = [&](int b, int k0) {
        const int cs = ac ^ ((arow >> 1) & 3);   // same for arow and arow+64
        const bf16_t* g0 = A + (size_t)arow * Kdim + (k0 + cs * 8);
        const bf16_t* g1 = A + (size_t)(arow + 64) * Kdim + (k0 + cs * 8);
        AS3 u32* l0 = (AS3 u32*)(void*)(&As[b][0] + (size_t)(wid * 16) * 32);
        AS3 u32* l1 = (AS3 u32*)(void*)(&As[b][0] + (size_t)(64 + wid * 16) * 32);
        __builtin_amdgcn_global_load_lds((const AS1 u32*)(const void*)g0, l0, 16, 0, 0);
        __builtin_amdgcn_global_load_lds((const AS1 u32*)(const void*)g1, l1, 16, 0, 0);
    };
    auto loadB = [&](int k0, float* v) {
        const float* sp = bsrc + (size_t)(k0 + kb) * Bstr;
        #pragma unroll
        for (int t = 0; t < 16; ++t) v[t] = sp[(size_t)t * Bstr];
    };
    auto writeB = [&](int b, const float* v) {
        u32 p[8];
        #pragma unroll
        for (int t = 0; t < 8; ++t) p[t] = pack2(v[2 * t], v[2 * t + 1]);
        uint4 w0, w1;
        w0.x = p[0]; w0.y = p[1]; w0.z = p[2]; w0.w = p[3];
        w1.x = p[4]; w1.y = p[5]; w1.z = p[6]; w1.w = p[7];
        *(uint4*)(&Bs[b][0] + (size_t)bn * BSTR + kb) = w0;
        *(uint4*)(&Bs[b][0] + (size_t)bn * BSTR + kb + 8) = w1;
    };

    {
        stageA(0, 0);
        float v[16]; loadB(0, v); writeB(0, v);
    }
    __syncthreads();

    int cur = 0;
    for (int kt = 0; kt < ksteps; ++kt) {
        const bool pf = (kt + 1 < ksteps);
        float vn[16];
        if (pf) {
            const int k1 = (kt + 1) << 5;
            stageA(cur ^ 1, k1);
            loadB(k1, vn);
        }
        bf16x8 af[4], bfr[4];
        #pragma unroll
        for (int i = 0; i < 4; ++i) {
            const int row = m_off + i * 16 + l15;
            af[i] = *(const bf16x8*)(&As[cur][0] + (size_t)row * 32 + (size_t)((lq ^ ((row >> 1) & 3)) * 8));
        }
        #pragma unroll
        for (int j = 0; j < 4; ++j) {
            const int n_ds = FUSED ? (wn * 32 + (j & 1) * 16 + (j >> 1) * 64)
                                   : (wn * 64 + j * 16);
            bfr[j] = *(const bf16x8*)(&Bs[cur][0] + (size_t)(n_ds + l15) * BSTR + lq * 8);
        }
        #pragma unroll
        for (int i = 0; i < 4; ++i)
            #pragma unroll
            for (int j = 0; j < 4; ++j)
                acc[i][j] = __builtin_amdgcn_mfma_f32_16x16x32_bf16(af[i], bfr[j], acc[i][j], 0, 0, 0);
        if (pf) writeB(cur ^ 1, vn);
        __syncthreads();
        cur ^= 1;
    }

    if (FUSED) {
        #pragma unroll
        for (int i = 0; i < 4; ++i)
            #pragma unroll
            for (int j = 0; j < 2; ++j) {
                const int n = wn * 32 + j * 16 + l15;
                #pragma unroll
                for (int r = 0; r < 4; ++r) {
                    const int m = m_off + i * 16 + lq * 4 + r;
                    Cout[(size_t)m * Ostr + n] = (bf16_t)silu_mul(acc[i][j][r], acc[i][j + 2][r]);
                }
            }
    } else {
        #pragma unroll
        for (int i = 0; i < 4; ++i)
            #pragma unroll
            for (int j = 0; j < 4; ++j) {
                const int n = wn * 64 + j * 16 + l15;
                #pragma unroll
                for (int r = 0; r < 4; ++r) {
                    const int m = m_off + i * 16 + lq * 4 + r;
                    Cout[(size_t)m * Ostr + n] = (bf16_t)acc[i][j][r];
                }
            }
    }
}

// ---------------- combine: weighted scatter of routed + shared add ----------
__global__ void k_combine(const bf16_t* __restrict__ down, const int* __restrict__ sop,
                          const float* __restrict__ wts, float* __restrict__ y) {
    int t = blockIdx.x;
    int d0 = threadIdx.x * 8;
    float a[8] = {0, 0, 0, 0, 0, 0, 0, 0};
    #pragma unroll
    for (int k = 0; k < KK; ++k) {
        int slot = sop[t * KK + k];
        float w = wts[t * KK + k];
        bf16x8 v = *(const bf16x8*)(down + (size_t)slot * DD + d0);
        #pragma unroll
        for (int j = 0; j < 8; ++j) a[j] += w * (float)v[j];
    }
    #pragma unroll
    for (int s = 0; s < SS; ++s) {
        bf16x8 v = *(const bf16x8*)(down + ((size_t)EE * CC + (size_t)s * TT + t) * DD + d0);
        #pragma unroll
        for (int j = 0; j < 8; ++j) a[j] += (float)v[j];
    }
    float4 o0, o1;
    o0.x = a[0]; o0.y = a[1]; o0.z = a[2]; o0.w = a[3];
    o1.x = a[4]; o1.y = a[5]; o1.z = a[6]; o1.w = a[7];
    *(float4*)(y + (size_t)t * DD + d0) = o0;
    *(float4*)(y + (size_t)t * DD + d0 + 4) = o1;
}

extern "C" void kernel_launch(void* const* d_in, const int* in_sizes, int n_in,
                              void* d_out, int out_size, void* d_ws, size_t ws_size,
                              hipStream_t stream) {
    (void)in_sizes; (void)n_in; (void)out_size; (void)ws_size;
    const float* x      = (const float*)d_in[0];
    const float* wts    = (const float*)d_in[1];
    const float* w_gu   = (const float*)d_in[2];
    const float* w_dn   = (const float*)d_in[3];
    const float* w_gu_s = (const float*)d_in[4];
    const float* w_dn_s = (const float*)d_in[5];
    const int*   indices= (const int*)d_in[6];
    float* y = (float*)d_out;

    char* ws = (char*)d_ws;
    size_t off = 0;
    auto alloc = [&](size_t bytes) {
        void* p = ws + off;
        off = (off + bytes + 255) & ~(size_t)255;
        return p;
    };
    int*    counts = (int*)alloc((size_t)EE * 4);
    int*    tok    = (int*)alloc((size_t)EE * CC * 4);
    int*    sop    = (int*)alloc((size_t)TT * KK * 4);
    bf16_t* xall   = (bf16_t*)alloc((size_t)(EE * CC + TT) * DD * 2);
    bf16_t* actb   = (bf16_t*)alloc((size_t)(EE * CC + SS * TT) * FF * 2);
    bf16_t* dnout  = (bf16_t*)alloc((size_t)(EE * CC + SS * TT) * DD * 2);

    hipMemsetAsync(counts, 0, EE * 4, stream);
    k_dispatch<<<(TT * KK + 255) / 256, 256, 0, stream>>>(indices, counts, tok, sop);
    k_gather<<<EE * CC + TT, 256, 0, stream>>>(x, tok, xall);

    // ---- gate_up (K=DD, B stride 2*FF), silu fused -> actb ----
    k_gemm_r<true><<<44 * EE, 256, 0, stream>>>(xall, w_gu, actb, DD, 2 * FF, FF, 44);
    k_gemm_s<true><<<dim3(FF / 64, TT / 128, SS), 256, 0, stream>>>(
        xall + (size_t)EE * CC * DD, w_gu_s, actb + (size_t)EE * CC * FF, DD, 2 * FF, FF, 0);

    // ---- down (K=FF, B stride DD) -> dnout ----
    k_gemm_r<false><<<32 * EE, 256, 0, stream>>>(actb, w_dn, dnout, FF, DD, DD, 32);
    k_gemm_s<false><<<dim3(DD / 128, TT / 128, SS), 256, 0, stream>>>(
        actb + (size_t)EE * CC * FF, w_dn_s, dnout + (size_t)EE * CC * DD, FF, DD, DD, TT);

    k_combine<<<TT, 256, 0, stream>>>(dnout, sop, wts, y);
}

// Round 4
// 1484.916 us; speedup vs baseline: 1.2803x; 1.0705x over previous
//
#include <hip/hip_runtime.h>
#include <hip/hip_bf16.h>

// Problem constants
#define TT 2048
#define KK 6
#define EE 32
#define DD 2048
#define FF 1408
#define SS 2
#define CC 384   // TT*KK/EE

typedef __bf16 bf16_t;
typedef __attribute__((ext_vector_type(8))) __bf16 bf16x8;
typedef __attribute__((ext_vector_type(4))) float f32x4;
typedef unsigned int u32;

#define AS1 __attribute__((address_space(1)))
#define AS3 __attribute__((address_space(3)))

__device__ __forceinline__ u32 f2bf(float f) {
    u32 u = __builtin_bit_cast(u32, f);
    return (u + 0x7fffu + ((u >> 16) & 1u)) >> 16;   // RNE, no NaN in data
}
__device__ __forceinline__ u32 pack2(float a, float b) {
    return f2bf(a) | (f2bf(b) << 16);
}
__device__ __forceinline__ float silu_mul(float g, float u) {
    return (g / (1.0f + __expf(-g))) * u;
}

// ---------------- dispatch: pair -> slot (balanced: exactly CC per expert) ----
__global__ void k_dispatch(const int* __restrict__ idx, int* __restrict__ counts,
                           int* __restrict__ tok, int* __restrict__ sop) {
    int p = blockIdx.x * 256 + threadIdx.x;
    if (p >= TT * KK) return;
    int e = idx[p];
    int pos = atomicAdd(&counts[e], 1);
    int slot = e * CC + pos;
    tok[slot] = p / KK;
    sop[p] = slot;
}

// ---------------- gather + fp32->bf16 convert --------------------------------
__global__ void k_gather(const float* __restrict__ x, const int* __restrict__ tok,
                         bf16_t* __restrict__ xall) {
    int row = blockIdx.x;
    int srow = (row < EE * CC) ? tok[row] : (row - EE * CC);
    const float* src = x + (size_t)srow * DD;
    bf16_t* dst = xall + (size_t)row * DD;
    int c0 = threadIdx.x * 8;
    float4 a = *(const float4*)(src + c0);
    float4 b = *(const float4*)(src + c0 + 4);
    uint4 o;
    o.x = pack2(a.x, a.y); o.y = pack2(a.z, a.w);
    o.z = pack2(b.x, b.y); o.w = pack2(b.z, b.w);
    *(uint4*)(dst + c0) = o;
}

#define BSTR 40

// =====================================================================
// Routed grouped GEMM, deep pipeline (counted vmcnt, never drains to 0).
// 512 threads (8 waves, 4m x 2n), tile M=384 (whole expert) x N=128, BK=32.
// B (fp32 weights) read EXACTLY ONCE per expert (no M-split).
// 3 A LDS buffers (glds, 2-iter latency window), 2 B LDS buffers.
// Per-iter vm ops: 8 B-loads then 3 A-glds. Steady waits:
//   A(t) ready  : newer = B(t+1)8 + A(t+1)3 + B(t+2)8 = 19 -> vmcnt(19)
//   B(t+1) regs : newer = A(t+1)3 + B(t+2)8 + A(t+2)3 = 14 -> vmcnt(14)
// =====================================================================
template<bool FUSED>
__global__ __launch_bounds__(512) void k_gemm_r(
    const bf16_t* __restrict__ Aall, const float* __restrict__ Br,
    bf16_t* __restrict__ Out, int Kdim, int Bstr, int Ostr, int NB)
{
    const int lin = blockIdx.x;
    const int xcd = lin & 7, jj = lin >> 3;
    const int e = xcd + 8 * (jj / NB);     // expert pinned to XCD e%8
    const int nblk = jj % NB;

    const bf16_t* A = Aall + (size_t)e * CC * Kdim;
    const float* Bbase = Br + (size_t)e * Kdim * Bstr;

    const int tid = threadIdx.x;
    const int lane = tid & 63, wid = tid >> 6;
    const int m_base = (wid >> 1) * 96, wn = wid & 1;
    const int l15 = lane & 15, lq = lane >> 4;
    const int arow = tid >> 2, ac = tid & 3;      // arow 0..127
    const int bn = tid & 127, kb = (tid >> 7) * 8; // kb in {0,8,16,24}

    const float* bsrc;
    bf16_t* Cout;
    if (FUSED) {   // N-tile = 64 gate cols + 64 up cols (same local index)
        bsrc = Bbase + ((bn & 64) ? FF : 0) + nblk * 64 + (bn & 63);
        Cout = Out + (size_t)e * CC * Ostr + nblk * 64;
    } else {
        bsrc = Bbase + nblk * 128 + bn;
        Cout = Out + (size_t)e * CC * Ostr + nblk * 128;
    }

    __shared__ __align__(16) bf16_t As[3][384 * 32];   // 3 x 24 KB
    __shared__ __align__(16) bf16_t Bs[2][128 * BSTR]; // 2 x 10 KB

    f32x4 acc[6][4] = {};
    const int ksteps = Kdim >> 5;   // 64 or 44 (even)

    auto stageA = [&](int kt, bf16_t* dst) {
        const int k0 = kt << 5;
        #pragma unroll
        for (int i = 0; i < 3; ++i) {
            const int row = i * 128 + arow;
            const int cs = ac ^ ((row >> 1) & 3);
            const bf16_t* g = A + (size_t)row * Kdim + (k0 + cs * 8);
            AS3 u32* l = (AS3 u32*)(void*)(dst + (size_t)(i * 128 + wid * 16) * 32);
            __builtin_amdgcn_global_load_lds((const AS1 u32*)(const void*)g, l, 16, 0, 0);
        }
    };
    auto loadB = [&](int kt, float* v) {
        const float* sp = bsrc + (size_t)((kt << 5) + kb) * Bstr;
        #pragma unroll
        for (int t = 0; t < 8; ++t) v[t] = sp[(size_t)t * Bstr];
    };
    auto writeB = [&](bf16_t* bbuf, const float* v) {
        uint4 w;
        w.x = pack2(v[0], v[1]); w.y = pack2(v[2], v[3]);
        w.z = pack2(v[4], v[5]); w.w = pack2(v[6], v[7]);
        *(uint4*)(bbuf + (size_t)bn * BSTR + kb) = w;
    };
    auto compute = [&](const bf16_t* abuf, const bf16_t* bbuf) {
        bf16x8 bfr[4];
        #pragma unroll
        for (int j = 0; j < 4; ++j) {
            const int n_ds = FUSED ? (wn * 32 + (j & 1) * 16 + (j >> 1) * 64)
                                   : (wn * 64 + j * 16);
            bfr[j] = *(const bf16x8*)(bbuf + (size_t)(n_ds + l15) * BSTR + lq * 8);
        }
        #pragma unroll
        for (int m = 0; m < 6; ++m) {
            const int row = m_base + m * 16 + l15;
            bf16x8 af = *(const bf16x8*)(abuf + (size_t)row * 32 + (size_t)((lq ^ ((row >> 1) & 3)) * 8));
            #pragma unroll
            for (int j = 0; j < 4; ++j)
                acc[m][j] = __builtin_amdgcn_mfma_f32_16x16x32_bf16(af, bfr[j], acc[m][j], 0, 0, 0);
        }
    };

    float vBa[8], vBb[8];
    bf16_t *aR = &As[0][0], *aS = &As[1][0], *aT = &As[2][0];

    // ---- prologue: B(0)->LDS, A(0),A(1) in flight, B(1) in regs ----
    loadB(0, vBa);                                      // 8 vm
    stageA(0, aR);                                      // 3 vm
    asm volatile("s_waitcnt vmcnt(3)" ::: "memory");    // B(0) regs ready
    writeB(&Bs[0][0], vBa);
    loadB(1, vBb);                                      // 8 vm
    stageA(1, aS);                                      // 3 vm
    asm volatile("s_waitcnt lgkmcnt(0)" ::: "memory");
    __builtin_amdgcn_s_barrier();

    for (int t = 0; t < ksteps - 2; t += 2) {
        // ---- sub-iter t (even): read Bs[0], write Bs[1] ----
        loadB(t + 2, vBa);
        asm volatile("s_waitcnt vmcnt(19)" ::: "memory");   // A(t) landed (self)
        asm volatile("s_waitcnt lgkmcnt(0)" ::: "memory");  // my B ds_write done
        __builtin_amdgcn_s_barrier();
        stageA(t + 2, aT);
        compute(aR, &Bs[0][0]);
        asm volatile("s_waitcnt vmcnt(14)" ::: "memory");   // B(t+1) regs ready
        writeB(&Bs[1][0], vBb);
        { bf16_t* tmp = aR; aR = aS; aS = aT; aT = tmp; }
        // ---- sub-iter t+1 (odd): read Bs[1], write Bs[0] ----
        loadB(t + 3, vBb);
        asm volatile("s_waitcnt vmcnt(19)" ::: "memory");
        asm volatile("s_waitcnt lgkmcnt(0)" ::: "memory");
        __builtin_amdgcn_s_barrier();
        stageA(t + 3, aT);
        compute(aR, &Bs[1][0]);
        asm volatile("s_waitcnt vmcnt(14)" ::: "memory");
        writeB(&Bs[0][0], vBa);
        { bf16_t* tmp = aR; aR = aS; aS = aT; aT = tmp; }
    }

    // ---- tail: tiles ksteps-2 (Bs[0]) and ksteps-1 (Bs[1]) ----
    asm volatile("s_waitcnt vmcnt(11)" ::: "memory");   // A(ks-2): newer = B(ks-1)8 + A(ks-1)3
    asm volatile("s_waitcnt lgkmcnt(0)" ::: "memory");
    __builtin_amdgcn_s_barrier();
    compute(aR, &Bs[0][0]);
    asm volatile("s_waitcnt vmcnt(3)" ::: "memory");    // B(ks-1) regs: newer = A(ks-1)3
    writeB(&Bs[1][0], vBb);
    asm volatile("s_waitcnt vmcnt(0)" ::: "memory");
    asm volatile("s_waitcnt lgkmcnt(0)" ::: "memory");
    __builtin_amdgcn_s_barrier();
    compute(aS, &Bs[1][0]);

    // ---- epilogue: C/D layout col=lane&15, row=quad*4+reg ----
    if (FUSED) {
        #pragma unroll
        for (int m = 0; m < 6; ++m)
            #pragma unroll
            for (int j = 0; j < 2; ++j) {
                const int n = wn * 32 + j * 16 + l15;
                #pragma unroll
                for (int r = 0; r < 4; ++r) {
                    const int mm = m_base + m * 16 + lq * 4 + r;
                    Cout[(size_t)mm * Ostr + n] = (bf16_t)silu_mul(acc[m][j][r], acc[m][j + 2][r]);
                }
            }
    } else {
        #pragma unroll
        for (int m = 0; m < 6; ++m)
            #pragma unroll
            for (int j = 0; j < 4; ++j) {
                const int n = wn * 64 + j * 16 + l15;
                #pragma unroll
                for (int r = 0; r < 4; ++r) {
                    const int mm = m_base + m * 16 + lq * 4 + r;
                    Cout[(size_t)mm * Ostr + n] = (bf16_t)acc[m][j][r];
                }
            }
    }
}

// =====================================================================
// Shared-expert GEMM, 256 threads (4 waves, 2m x 2n), tile 128 x 128, BK=32.
// Same deep pipeline. Per-iter vm ops: 16 B-loads + 2 A-glds.
//   A(t) ready  : newer = 16+2+16 = 34 -> vmcnt(34)
//   B(t+1) regs : newer = 2+16+2  = 20 -> vmcnt(20)
// Grid pinned so all 16 m-blocks of one (s, n-slab) share an XCD (B in L2).
// =====================================================================
template<bool FUSED>
__global__ __launch_bounds__(256) void k_gemm_s(
    const bf16_t* __restrict__ Ash, const float* __restrict__ Bsh,
    bf16_t* __restrict__ Out, int Kdim, int Bstr, int Ostr, int ash_stride,
    int nkeys, int KQ, int NBs)
{
    const int b = blockIdx.x;
    const int xcd = b & 7, jj = b >> 3;
    const int m = jj / KQ, kq = jj % KQ;
    const int key = kq * 8 + xcd;
    if (key >= nkeys) return;
    const int s = key / NBs, nb = key % NBs;

    const bf16_t* A = Ash + ((size_t)s * ash_stride + (size_t)m * 128) * Kdim;
    const float* Bp = Bsh + (size_t)s * Kdim * Bstr;

    const int tid = threadIdx.x;
    const int lane = tid & 63, wid = tid >> 6;
    const int m_off = (wid >> 1) * 64, wn = wid & 1;
    const int l15 = lane & 15, lq = lane >> 4;
    const int arow = tid >> 2, ac = tid & 3;
    const int bn = tid & 127, kb = (tid >> 7) * 16;

    const float* bsrc;
    bf16_t* Cout;
    if (FUSED) {
        bsrc = Bp + (((tid >> 6) & 1) ? FF : 0) + nb * 64 + (tid & 63);
        Cout = Out + ((size_t)s * TT + (size_t)m * 128) * Ostr + nb * 64;
    } else {
        bsrc = Bp + nb * 128 + bn;
        Cout = Out + ((size_t)s * TT + (size_t)m * 128) * Ostr + nb * 128;
    }

    __shared__ __align__(16) bf16_t As[3][128 * 32];   // 3 x 8 KB
    __shared__ __align__(16) bf16_t Bs[2][128 * BSTR]; // 2 x 10 KB

    f32x4 acc[4][4] = {};
    const int ksteps = Kdim >> 5;   // 64 or 44 (even)

    auto stageA = [&](int kt, bf16_t* dst) {
        const int k0 = kt << 5;
        #pragma unroll
        for (int i = 0; i < 2; ++i) {
            const int row = i * 64 + arow;
            const int cs = ac ^ ((row >> 1) & 3);
            const bf16_t* g = A + (size_t)row * Kdim + (k0 + cs * 8);
            AS3 u32* l = (AS3 u32*)(void*)(dst + (size_t)(i * 64 + wid * 16) * 32);
            __builtin_amdgcn_global_load_lds((const AS1 u32*)(const void*)g, l, 16, 0, 0);
        }
    };
    auto loadB = [&](int kt, float* v) {
        const float* sp = bsrc + (size_t)((kt << 5) + kb) * Bstr;
        #pragma unroll
        for (int t = 0; t < 16; ++t) v[t] = sp[(size_t)t * Bstr];
    };
    auto writeB = [&](bf16_t* bbuf, const float* v) {
        u32 p[8];
        #pragma unroll
        for (int t = 0; t < 8; ++t) p[t] = pack2(v[2 * t], v[2 * t + 1]);
        uint4 w0, w1;
        w0.x = p[0]; w0.y = p[1]; w0.z = p[2]; w0.w = p[3];
        w1.x = p[4]; w1.y = p[5]; w1.z = p[6]; w1.w = p[7];
        *(uint4*)(bbuf + (size_t)bn * BSTR + kb) = w0;
        *(uint4*)(bbuf + (size_t)bn * BSTR + kb + 8) = w1;
    };
    auto compute = [&](const bf16_t* abuf, const bf16_t* bbuf) {
        bf16x8 af[4], bfr[4];
        #pragma unroll
        for (int i = 0; i < 4; ++i) {
            const int row = m_off + i * 16 + l15;
            af[i] = *(const bf16x8*)(abuf + (size_t)row * 32 + (size_t)((lq ^ ((row >> 1) & 3)) * 8));
        }
        #pragma unroll
        for (int j = 0; j < 4; ++j) {
            const int n_ds = FUSED ? (wn * 32 + (j & 1) * 16 + (j >> 1) * 64)
                                   : (wn * 64 + j * 16);
            bfr[j] = *(const bf16x8*)(bbuf + (size_t)(n_ds + l15) * BSTR + lq * 8);
        }
        #pragma unroll
        for (int i = 0; i < 4; ++i)
            #pragma unroll
            for (int j = 0; j < 4; ++j)
                acc[i][j] = __builtin_amdgcn_mfma_f32_16x16x32_bf16(af[i], bfr[j], acc[i][j], 0, 0, 0);
    };

    float vBa[16], vBb[16];
    bf16_t *aR = &As[0][0], *aS = &As[1][0], *aT = &As[2][0];

    // ---- prologue ----
    loadB(0, vBa);                                      // 16 vm
    stageA(0, aR);                                      // 2 vm
    asm volatile("s_waitcnt vmcnt(2)" ::: "memory");    // B(0) regs ready
    writeB(&Bs[0][0], vBa);
    loadB(1, vBb);
    stageA(1, aS);
    asm volatile("s_waitcnt lgkmcnt(0)" ::: "memory");
    __builtin_amdgcn_s_barrier();

    for (int t = 0; t < ksteps - 2; t += 2) {
        // ---- sub-iter t (even) ----
        loadB(t + 2, vBa);
        asm volatile("s_waitcnt vmcnt(34)" ::: "memory");
        asm volatile("s_waitcnt lgkmcnt(0)" ::: "memory");
        __builtin_amdgcn_s_barrier();
        stageA(t + 2, aT);
        compute(aR, &Bs[0][0]);
        asm volatile("s_waitcnt vmcnt(20)" ::: "memory");
        writeB(&Bs[1][0], vBb);
        { bf16_t* tmp = aR; aR = aS; aS = aT; aT = tmp; }
        // ---- sub-iter t+1 (odd) ----
        loadB(t + 3, vBb);
        asm volatile("s_waitcnt vmcnt(34)" ::: "memory");
        asm volatile("s_waitcnt lgkmcnt(0)" ::: "memory");
        __builtin_amdgcn_s_barrier();
        stageA(t + 3, aT);
        compute(aR, &Bs[1][0]);
        asm volatile("s_waitcnt vmcnt(20)" ::: "memory");
        writeB(&Bs[0][0], vBa);
        { bf16_t* tmp = aR; aR = aS; aS = aT; aT = tmp; }
    }

    // ---- tail ----
    asm volatile("s_waitcnt vmcnt(18)" ::: "memory");   // A(ks-2): newer = 16 + 2
    asm volatile("s_waitcnt lgkmcnt(0)" ::: "memory");
    __builtin_amdgcn_s_barrier();
    compute(aR, &Bs[0][0]);
    asm volatile("s_waitcnt vmcnt(2)" ::: "memory");    // B(ks-1) regs
    writeB(&Bs[1][0], vBb);
    asm volatile("s_waitcnt vmcnt(0)" ::: "memory");
    asm volatile("s_waitcnt lgkmcnt(0)" ::: "memory");
    __builtin_amdgcn_s_barrier();
    compute(aS, &Bs[1][0]);

    if (FUSED) {
        #pragma unroll
        for (int i = 0; i < 4; ++i)
            #pragma unroll
            for (int j = 0; j < 2; ++j) {
                const int n = wn * 32 + j * 16 + l15;
                #pragma unroll
                for (int r = 0; r < 4; ++r) {
                    const int mm = m_off + i * 16 + lq * 4 + r;
                    Cout[(size_t)mm * Ostr + n] = (bf16_t)silu_mul(acc[i][j][r], acc[i][j + 2][r]);
                }
            }
    } else {
        #pragma unroll
        for (int i = 0; i < 4; ++i)
            #pragma unroll
            for (int j = 0; j < 4; ++j) {
                const int n = wn * 64 + j * 16 + l15;
                #pragma unroll
                for (int r = 0; r < 4; ++r) {
                    const int mm = m_off + i * 16 + lq * 4 + r;
                    Cout[(size_t)mm * Ostr + n] = (bf16_t)acc[i][j][r];
                }
            }
    }
}

// ---------------- combine: weighted scatter of routed + shared add ----------
__global__ void k_combine(const bf16_t* __restrict__ down, const int* __restrict__ sop,
                          const float* __restrict__ wts, float* __restrict__ y) {
    int t = blockIdx.x;
    int d0 = threadIdx.x * 8;
    float a[8] = {0, 0, 0, 0, 0, 0, 0, 0};
    #pragma unroll
    for (int k = 0; k < KK; ++k) {
        int slot = sop[t * KK + k];
        float w = wts[t * KK + k];
        bf16x8 v = *(const bf16x8*)(down + (size_t)slot * DD + d0);
        #pragma unroll
        for (int j = 0; j < 8; ++j) a[j] += w * (float)v[j];
    }
    #pragma unroll
    for (int s = 0; s < SS; ++s) {
        bf16x8 v = *(const bf16x8*)(down + ((size_t)EE * CC + (size_t)s * TT + t) * DD + d0);
        #pragma unroll
        for (int j = 0; j < 8; ++j) a[j] += (float)v[j];
    }
    float4 o0, o1;
    o0.x = a[0]; o0.y = a[1]; o0.z = a[2]; o0.w = a[3];
    o1.x = a[4]; o1.y = a[5]; o1.z = a[6]; o1.w = a[7];
    *(float4*)(y + (size_t)t * DD + d0) = o0;
    *(float4*)(y + (size_t)t * DD + d0 + 4) = o1;
}

extern "C" void kernel_launch(void* const* d_in, const int* in_sizes, int n_in,
                              void* d_out, int out_size, void* d_ws, size_t ws_size,
                              hipStream_t stream) {
    (void)in_sizes; (void)n_in; (void)out_size; (void)ws_size;
    const float* x      = (const float*)d_in[0];
    const float* wts    = (const float*)d_in[1];
    const float* w_gu   = (const float*)d_in[2];
    const float* w_dn   = (const float*)d_in[3];
    const float* w_gu_s = (const float*)d_in[4];
    const float* w_dn_s = (const float*)d_in[5];
    const int*   indices= (const int*)d_in[6];
    float* y = (float*)d_out;

    char* ws = (char*)d_ws;
    size_t off = 0;
    auto alloc = [&](size_t bytes) {
        void* p = ws + off;
        off = (off + bytes + 255) & ~(size_t)255;
        return p;
    };
    int*    counts = (int*)alloc((size_t)EE * 4);
    int*    tok    = (int*)alloc((size_t)EE * CC * 4);
    int*    sop    = (int*)alloc((size_t)TT * KK * 4);
    bf16_t* xall   = (bf16_t*)alloc((size_t)(EE * CC + TT) * DD * 2);
    bf16_t* actb   = (bf16_t*)alloc((size_t)(EE * CC + SS * TT) * FF * 2);
    bf16_t* dnout  = (bf16_t*)alloc((size_t)(EE * CC + SS * TT) * DD * 2);

    hipMemsetAsync(counts, 0, EE * 4, stream);
    k_dispatch<<<(TT * KK + 255) / 256, 256, 0, stream>>>(indices, counts, tok, sop);
    k_gather<<<EE * CC + TT, 256, 0, stream>>>(x, tok, xall);

    // ---- gate_up (K=DD, B stride 2*FF), silu fused -> actb ----
    // routed: 22 n-blocks x 32 experts (FF/64 fused cols per block)
    k_gemm_r<true><<<EE * 22, 512, 0, stream>>>(xall, w_gu, actb, DD, 2 * FF, FF, 22);
    // shared: nkeys = SS*22 = 44, KQ = 6 -> grid 8*6*16 = 768
    k_gemm_s<true><<<8 * 6 * 16, 256, 0, stream>>>(
        xall + (size_t)EE * CC * DD, w_gu_s, actb + (size_t)EE * CC * FF,
        DD, 2 * FF, FF, 0, 44, 6, 22);

    // ---- down (K=FF, B stride DD) -> dnout ----
    k_gemm_r<false><<<EE * 16, 512, 0, stream>>>(actb, w_dn, dnout, FF, DD, DD, 16);
    // shared: nkeys = SS*16 = 32, KQ = 4 -> grid 8*4*16 = 512
    k_gemm_s<false><<<8 * 4 * 16, 256, 0, stream>>>(
        actb + (size_t)EE * CC * FF, w_dn_s, dnout + (size_t)EE * CC * DD,
        FF, DD, DD, TT, 32, 4, 16);

    k_combine<<<TT, 256, 0, stream>>>(dnout, sop, wts, y);
}